// Round 9
// baseline (134.080 us; speedup 1.0000x reference)
//
#include <hip/hip_runtime.h>
#include <math.h>

#define IMG 512

typedef __attribute__((ext_vector_type(4))) short short4_t;
typedef __attribute__((ext_vector_type(8))) short short8;
typedef __attribute__((ext_vector_type(4))) float f32x4;
typedef __attribute__((ext_vector_type(16))) float f32x16;
typedef __attribute__((ext_vector_type(2))) unsigned int u32x2;
typedef __attribute__((ext_vector_type(4))) unsigned int u32x4;

__device__ __forceinline__ unsigned short f2bf(float f) {
  unsigned u = __builtin_bit_cast(unsigned, f);
  u += 0x7FFFu + ((u >> 16) & 1u);  // RNE
  return (unsigned short)(u >> 16);
}
// packed f32x2 -> bf16x2 (RNE), single VALU op
__device__ __forceinline__ unsigned cvtpk(float lo, float hi) {
  unsigned r;
  asm("v_cvt_pk_bf16_f32 %0, %1, %2" : "=v"(r) : "v"(lo), "v"(hi));
  return r;
}

// ---------------------------------------------------------------------------
// k_prep: lane-major conv1 A-fragments (32x32x16, K padded 12->16 per kk=dy).
// ---------------------------------------------------------------------------
__global__ __launch_bounds__(256) void k_prep(const float* __restrict__ w1,
                                              unsigned short* __restrict__ w1f) {
  const int t = threadIdx.x;
  if (t < 192) {
    const int kk = t >> 6, lane = t & 63;
    const int oc = lane & 31, hi = lane >> 5;
#pragma unroll
    for (int j = 0; j < 8; ++j) {
      const int dxp = 2 * hi + (j >> 2), ic = j & 3;
      float v = (dxp < 3) ? w1[((oc * 4 + ic) * 3 + kk) * 3 + dxp] : 0.f;
      w1f[(kk * 64 + lane) * 8 + j] = f2bf(v);
    }
  }
}

// ---------------------------------------------------------------------------
// Pass 1: conv1 (bf16 MFMA 32x32x16) + ReLU + pool over exact 32x32 tiles.
// ---------------------------------------------------------------------------
__global__ __launch_bounds__(256, 3) void k_pool(
    const float* __restrict__ x, const unsigned short* __restrict__ w1f,
    const float* __restrict__ b1, float* __restrict__ red_out, int use_atomic) {
  __shared__ unsigned short xs[34 * 40 * 4];
  __shared__ float pools[4][2][16];
  const int bid = blockIdx.x;
  const int swz = (bid & 7) * 512 + (bid >> 3);  // XCD-contiguous
  const int bx = swz & 15, by = (swz >> 4) & 15, n = swz >> 8;
  const int x0 = bx * 32, y0 = by * 32;
  const int t = threadIdx.x, lane = t & 63, wv = t >> 6;
  const int hi = lane >> 5;

  short8 A1[3];
#pragma unroll
  for (int kk = 0; kk < 3; ++kk)
    A1[kk] = *(const short8*)&w1f[(kk * 64 + lane) * 8];
  float bias_r[16];
#pragma unroll
  for (int r = 0; r < 16; ++r) {
    float bl = b1[(r & 3) + 8 * (r >> 2)], bh = b1[(r & 3) + 8 * (r >> 2) + 4];
    bias_r[r] = hi ? bh : bl;
  }

  const int sx = x0 - 4;
  const long CS = (long)IMG * IMG;
  for (int i = t; i < 340; i += 256) {
    const int row = i / 10, cb = i % 10;
    const int gy = y0 - 1 + row, gx0 = sx + cb * 4;
    f32x4 v0 = {0.f, 0.f, 0.f, 0.f}, v1 = v0, v2 = v0, v3 = v0;
    if (gy >= 0 && gy < IMG && gx0 >= 0 && gx0 < IMG) {
      const float* p = x + (((long)(n * 4) * IMG + gy) * IMG + gx0);
      v0 = *(const f32x4*)p;
      v1 = *(const f32x4*)(p + CS);
      v2 = *(const f32x4*)(p + 2 * CS);
      v3 = *(const f32x4*)(p + 3 * CS);
    }
    unsigned short* d = &xs[(row * 40 + cb * 4) * 4];
#pragma unroll
    for (int j = 0; j < 4; ++j) {
      u32x2 w;
      w[0] = cvtpk(v0[j], v1[j]);
      w[1] = cvtpk(v2[j], v3[j]);
      *(u32x2*)(d + j * 4) = w;
    }
  }
  __syncthreads();

  float pacc[16];
#pragma unroll
  for (int r = 0; r < 16; ++r) pacc[r] = 0.f;
  const int cx0 = (lane & 31) + 2 * hi + 3;
  const unsigned short* pP = &xs[((wv * 8) * 40 + cx0) * 4];
#define LOADP(K)                                                              \
  __builtin_shufflevector(*(const short4_t*)(pP + (K)*160),                   \
                          *(const short4_t*)(pP + (K)*160 + 4), 0, 1, 2, 3,   \
                          4, 5, 6, 7)
  short8 Ba, Bb, Bc;
  Ba = LOADP(0);
  Bb = LOADP(1);
#define P_ITER(IT, B0, B1, B2)                                                \
  {                                                                           \
    B2 = LOADP((IT) + 2);                                                     \
    f32x16 C;                                                                 \
    _Pragma("unroll") for (int r = 0; r < 16; ++r) C[r] = bias_r[r];          \
    C = __builtin_amdgcn_mfma_f32_32x32x16_bf16(A1[0], B0, C, 0, 0, 0);       \
    C = __builtin_amdgcn_mfma_f32_32x32x16_bf16(A1[1], B1, C, 0, 0, 0);       \
    C = __builtin_amdgcn_mfma_f32_32x32x16_bf16(A1[2], B2, C, 0, 0, 0);       \
    _Pragma("unroll") for (int r = 0; r < 16; ++r)                            \
        pacc[r] += fmaxf(C[r], 0.f);                                          \
  }
  P_ITER(0, Ba, Bb, Bc)
  P_ITER(1, Bb, Bc, Ba)
  P_ITER(2, Bc, Ba, Bb)
  P_ITER(3, Ba, Bb, Bc)
  P_ITER(4, Bb, Bc, Ba)
  P_ITER(5, Bc, Ba, Bb)
  P_ITER(6, Ba, Bb, Bc)
  P_ITER(7, Bb, Bc, Ba)
#undef P_ITER
#undef LOADP
#pragma unroll
  for (int r = 0; r < 16; ++r) {
#pragma unroll
    for (int m = 1; m < 32; m <<= 1) pacc[r] += __shfl_xor(pacc[r], m);
  }
  if ((lane & 31) == 0) {
#pragma unroll
    for (int r = 0; r < 16; ++r) pools[wv][hi][r] = pacc[r];
  }
  __syncthreads();
  if (t < 32) {
    const int c = t;
    const int hic = (c >> 2) & 1, reg = (c & 3) + 4 * (c >> 3);
    float s = pools[0][hic][reg] + pools[1][hic][reg] + pools[2][hic][reg] +
              pools[3][hic][reg];
    if (use_atomic) {
      atomicAdd(&red_out[n * 32 + c], s);
    } else {
      red_out[(n * 256 + by * 16 + bx) * 32 + c] = s;
    }
  }
}

// ---------------------------------------------------------------------------
// Pass 2: reduce partials (det path) + SE head + emit conv2 A-fragments:
// w2f[((n*18+s)*64+lane)*8+j], s=(dyy*3+dx), lane:(row16=oc+4*yo, cg),
// value = (0<=dyy-yo<3) ? w2[oc][c=cg*8+j][dyy-yo][dx]*p[c] : 0
// ---------------------------------------------------------------------------
__global__ __launch_bounds__(256) void k_se(
    const float* __restrict__ partials, const float* __restrict__ sums,
    const float* __restrict__ w_se1, const float* __restrict__ b_se1,
    const float* __restrict__ w_se2, const float* __restrict__ b_se2,
    const float* __restrict__ w2, unsigned short* __restrict__ w2f, int det) {
  const int n = blockIdx.x, t = threadIdx.x;
  __shared__ float red[8][32];
  __shared__ float mean_s[32], f1[16], p[32];
  if (det) {
    const int c = t & 31, s = t >> 5;
    float a = 0.f;
    for (int i = s * 32; i < s * 32 + 32; ++i)
      a += partials[(n * 256 + i) * 32 + c];
    red[s][c] = a;
    __syncthreads();
    if (t < 32) {
      float v = 0.f;
#pragma unroll
      for (int s2 = 0; s2 < 8; ++s2) v += red[s2][t];
      mean_s[t] = v * (1.0f / (512.f * 512.f));
    }
  } else {
    if (t < 32) mean_s[t] = sums[n * 32 + t] * (1.0f / (512.f * 512.f));
  }
  __syncthreads();
  if (t < 16) {
    float a = b_se1[t];
#pragma unroll
    for (int c = 0; c < 32; ++c) a += w_se1[t * 32 + c] * mean_s[c];
    f1[t] = fmaxf(a, 0.f);
  }
  __syncthreads();
  if (t < 32) {
    float a = b_se2[t];
#pragma unroll
    for (int c = 0; c < 16; ++c) a += w_se2[t * 16 + c] * f1[c];
    p[t] = 1.f / (1.f + expf(-a));
  }
  __syncthreads();
  for (int i = t; i < 9216; i += 256) {
    const int s = i >> 9, rem = i & 511, lane2 = rem >> 3, j = rem & 7;
    const int oc = lane2 & 3, yo = (lane2 >> 2) & 3, cg = lane2 >> 4;
    const int c = cg * 8 + j;
    const int dyy = s / 3, dx = s - dyy * 3, dy = dyy - yo;
    float v = 0.f;
    if (dy >= 0 && dy < 3) v = w2[(oc * 32 + c) * 9 + dy * 3 + dx] * p[c];
    w2f[((n * 18 + s) * 64 + lane2) * 8 + j] = f2bf(v);
  }
}

// ---------------------------------------------------------------------------
// Pass 3: MULTI-TILE persistent block. Each block: 4 vertically-stacked
// 30x16 tiles. Weights/addressing hoisted (A2 loaded once per 4 tiles);
// cross-tile pipelined staging: stage_issue(t+1) BEFORE conv1(t) so conv1
// covers HBM latency; stage_write lands after the conv1->conv2 barrier
// into the other xs buffer. 2 barriers/tile.
// hs [18][32 px][32 c] bf16, swizzle q2=(px>>1)&3 on 16B blocks.
// ---------------------------------------------------------------------------
__global__ __launch_bounds__(256, 3) void k_main(
    const float* __restrict__ x, const unsigned short* __restrict__ w1f,
    const float* __restrict__ b1, const unsigned short* __restrict__ w2f,
    const float* __restrict__ b2, float* __restrict__ out) {
  __shared__ unsigned short xs[2][20 * 40 * 4];
  __shared__ unsigned short hs[18 * 32 * 32];
  const int bid = blockIdx.x;
  const int swz = (bid & 7) * 288 + (bid >> 3);  // XCD-contiguous, 2304 wgs
  const int bx = swz % 18;
  const int q = swz / 18;
  const int byq = q & 7, n = q >> 3;
  const int x0 = bx * 30;
  const int ybase = byq * 64;
  const int t = threadIdx.x, lane = t & 63, wv = t >> 6;
  const int hi = lane >> 5;
  const int n4 = n * 4;
  const long CS = (long)IMG * IMG;

  // ---- conv2 A-frags (once per block; latency hides under prologue)
  const unsigned short* w2b = w2f + (size_t)n * 9216 + lane * 8;
  short8 A2_0 = *(const short8*)(w2b + 0 * 512);
  short8 A2_1 = *(const short8*)(w2b + 1 * 512);
  short8 A2_2 = *(const short8*)(w2b + 2 * 512);
  short8 A2_3 = *(const short8*)(w2b + 3 * 512);
  short8 A2_4 = *(const short8*)(w2b + 4 * 512);
  short8 A2_5 = *(const short8*)(w2b + 5 * 512);
  short8 A2_6 = *(const short8*)(w2b + 6 * 512);
  short8 A2_7 = *(const short8*)(w2b + 7 * 512);
  short8 A2_8 = *(const short8*)(w2b + 8 * 512);
  short8 A2_9 = *(const short8*)(w2b + 9 * 512);
  short8 A2_10 = *(const short8*)(w2b + 10 * 512);
  short8 A2_11 = *(const short8*)(w2b + 11 * 512);
  short8 A2_12 = *(const short8*)(w2b + 12 * 512);
  short8 A2_13 = *(const short8*)(w2b + 13 * 512);
  short8 A2_14 = *(const short8*)(w2b + 14 * 512);
  short8 A2_15 = *(const short8*)(w2b + 15 * 512);
  short8 A2_16 = *(const short8*)(w2b + 16 * 512);
  short8 A2_17 = *(const short8*)(w2b + 17 * 512);
  asm volatile("" ::"v"(A2_0), "v"(A2_1), "v"(A2_2), "v"(A2_3), "v"(A2_4),
               "v"(A2_5), "v"(A2_6), "v"(A2_7), "v"(A2_8), "v"(A2_9),
               "v"(A2_10), "v"(A2_11), "v"(A2_12), "v"(A2_13), "v"(A2_14),
               "v"(A2_15), "v"(A2_16), "v"(A2_17));

  short8 A1[3];
#pragma unroll
  for (int kk = 0; kk < 3; ++kk)
    A1[kk] = *(const short8*)&w1f[(kk * 64 + lane) * 8];
  float bias_r[16];
#pragma unroll
  for (int r = 0; r < 16; ++r) {
    float bl = b1[(r & 3) + 8 * (r >> 2)], bh = b1[(r & 3) + 8 * (r >> 2) + 4];
    bias_r[r] = hi ? bh : bl;
  }

  // ---- staging state (task: t<200 -> row=t/10, colblock=t%10)
  const int sx = (x0 - 4) & ~3;
  const int srow = t / 10, cb = t % 10;
  const int gxs = sx + cb * 4;
  const bool scol = (t < 200) && (gxs >= 0) && (gxs < IMG);
  const f32x4 zf = {0.f, 0.f, 0.f, 0.f};
  f32x4 sv0 = zf, sv1 = zf, sv2 = zf, sv3 = zf;

  auto stage_issue = [&](int ytile) {
    const int gy = ytile - 2 + srow;
    if (scol && gy >= 0 && gy < IMG) {
      const float* p = x + (((long)n4 * IMG + gy) * IMG + gxs);
      sv0 = *(const f32x4*)p;
      sv1 = *(const f32x4*)(p + CS);
      sv2 = *(const f32x4*)(p + 2 * CS);
      sv3 = *(const f32x4*)(p + 3 * CS);
    } else {
      sv0 = zf; sv1 = zf; sv2 = zf; sv3 = zf;
    }
  };
  auto stage_write = [&](unsigned short* xbuf) {
    if (t < 200) {
      unsigned short* d = &xbuf[(srow * 40 + cb * 4) * 4];
      u32x4 w0, w1;
      w0[0] = cvtpk(sv0[0], sv1[0]); w0[1] = cvtpk(sv2[0], sv3[0]);
      w0[2] = cvtpk(sv0[1], sv1[1]); w0[3] = cvtpk(sv2[1], sv3[1]);
      w1[0] = cvtpk(sv0[2], sv1[2]); w1[1] = cvtpk(sv2[2], sv3[2]);
      w1[2] = cvtpk(sv0[3], sv1[3]); w1[3] = cvtpk(sv2[3], sv3[3]);
      *(u32x4*)d = w0;
      *(u32x4*)(d + 8) = w1;
    }
  };

  // ---- conv1 constants
  const int px = lane & 31;
  const int cx0 = px + 2 * hi + (x0 - 2 - sx);  // halo-aware delta
  const int q2 = (px >> 1) & 3;
  const int gxc = x0 - 1 + px;
  const bool colok = (gxc >= 0) && (gxc < IMG);
  const bool col_int = (x0 >= 1) && (x0 + 30 < IMG);
  const int R0 = (wv < 2) ? wv * 5 : 10 + (wv - 2) * 4;  // rows/wave 5,5,4,4

  auto conv1_tile = [&](const unsigned short* xbuf, int ytile) {
    const unsigned short* pR = &xbuf[(R0 * 40 + cx0) * 4];
#define LOADX(K)                                                              \
  __builtin_shufflevector(*(const short4_t*)(pR + (K)*160),                   \
                          *(const short4_t*)(pR + (K)*160 + 4), 0, 1, 2, 3,   \
                          4, 5, 6, 7)
    short8 Ba, Bb, Bc;
    Ba = LOADX(0);
    Bb = LOADX(1);
#define C1_ITER(IT, B0, B1, B2)                                               \
  {                                                                           \
    B2 = LOADX((IT) + 2);                                                     \
    const int hy = R0 + (IT);                                                 \
    const int yi = ytile - 1 + hy;                                            \
    const bool row_ok = (yi >= 0) && (yi < IMG);                              \
    f32x16 C;                                                                 \
    _Pragma("unroll") for (int r = 0; r < 16; ++r) C[r] = bias_r[r];          \
    C = __builtin_amdgcn_mfma_f32_32x32x16_bf16(A1[0], B0, C, 0, 0, 0);       \
    C = __builtin_amdgcn_mfma_f32_32x32x16_bf16(A1[1], B1, C, 0, 0, 0);       \
    C = __builtin_amdgcn_mfma_f32_32x32x16_bf16(A1[2], B2, C, 0, 0, 0);       \
    const int usb = hy * 1024 + px * 32 + (hi << 2);                          \
    if (row_ok && col_int) {                                                  \
      _Pragma("unroll") for (int g = 0; g < 4; ++g) {                         \
        u32x2 w;                                                              \
        w[0] = cvtpk(fmaxf(C[4 * g + 0], 0.f), fmaxf(C[4 * g + 1], 0.f));     \
        w[1] = cvtpk(fmaxf(C[4 * g + 2], 0.f), fmaxf(C[4 * g + 3], 0.f));     \
        *(u32x2*)&hs[usb + ((g ^ q2) << 3)] = w;                              \
      }                                                                       \
    } else if (row_ok) {                                                      \
      _Pragma("unroll") for (int g = 0; g < 4; ++g) {                         \
        unsigned p01 =                                                        \
            cvtpk(fmaxf(C[4 * g + 0], 0.f), fmaxf(C[4 * g + 1], 0.f));        \
        unsigned p23 =                                                        \
            cvtpk(fmaxf(C[4 * g + 2], 0.f), fmaxf(C[4 * g + 3], 0.f));        \
        u32x2 w;                                                              \
        w[0] = colok ? p01 : 0u;                                              \
        w[1] = colok ? p23 : 0u;                                              \
        *(u32x2*)&hs[usb + ((g ^ q2) << 3)] = w;                              \
      }                                                                       \
    } else {                                                                  \
      u32x2 z;                                                                \
      z[0] = 0u;                                                              \
      z[1] = 0u;                                                              \
      _Pragma("unroll") for (int g = 0; g < 4; ++g)                           \
          *(u32x2*)&hs[usb + ((g ^ q2) << 3)] = z;                            \
    }                                                                         \
  }
    C1_ITER(0, Ba, Bb, Bc)
    C1_ITER(1, Bb, Bc, Ba)
    C1_ITER(2, Bc, Ba, Bb)
    C1_ITER(3, Ba, Bb, Bc)
    if (wv < 2) C1_ITER(4, Bb, Bc, Ba)
#undef C1_ITER
#undef LOADX
  };

  // ---- conv2 constants
  const int px16 = lane & 15, cg = lane >> 4;
  const int grp = wv & 1, wrow = wv >> 1;
  const int ox = grp * 16 + px16;
  const int yo = lane >> 4;
  const int gxo = x0 + ox;
  const bool epi_ok = (ox < 30) && (gxo < IMG);
  const float b20 = b2[0], b21 = b2[1], b22 = b2[2], b23 = b2[3];
  int ph0 = ox, ph1 = ox + 1, ph2 = ox + 2;
  ph2 = ph2 < 31 ? ph2 : 31;
  ph1 = ph1 < 31 ? ph1 : 31;
  const int ba0 = ph0 * 64 + ((cg ^ ((ph0 >> 1) & 3)) << 4);
  const int ba1 = ph1 * 64 + ((cg ^ ((ph1 >> 1) & 3)) << 4);
  const int ba2 = ph2 * 64 + ((cg ^ ((ph2 >> 1) & 3)) << 4);
  const char* hb = (const char*)hs + (wrow * 8) * 2048;

  auto conv2_tile = [&](int ytile) {
    f32x4 CA = {b20, b21, b22, b23};
    f32x4 CB = {b20, b21, b22, b23};
    short8 F0, F1, F2;
#define LOADF(R)                                                              \
  F0 = *(const short8*)(hb + (R)*2048 + ba0);                                 \
  F1 = *(const short8*)(hb + (R)*2048 + ba1);                                 \
  F2 = *(const short8*)(hb + (R)*2048 + ba2);
#define MFA(S0, S1, S2)                                                       \
  CA = __builtin_amdgcn_mfma_f32_16x16x32_bf16(A2_##S0, F0, CA, 0, 0, 0);     \
  CA = __builtin_amdgcn_mfma_f32_16x16x32_bf16(A2_##S1, F1, CA, 0, 0, 0);     \
  CA = __builtin_amdgcn_mfma_f32_16x16x32_bf16(A2_##S2, F2, CA, 0, 0, 0);
#define MFB(S0, S1, S2)                                                       \
  CB = __builtin_amdgcn_mfma_f32_16x16x32_bf16(A2_##S0, F0, CB, 0, 0, 0);     \
  CB = __builtin_amdgcn_mfma_f32_16x16x32_bf16(A2_##S1, F1, CB, 0, 0, 0);     \
  CB = __builtin_amdgcn_mfma_f32_16x16x32_bf16(A2_##S2, F2, CB, 0, 0, 0);
    __builtin_amdgcn_s_setprio(1);
    LOADF(0) MFA(0, 1, 2)
    LOADF(1) MFA(3, 4, 5)
    LOADF(2) MFA(6, 7, 8)
    LOADF(3) MFA(9, 10, 11)
    LOADF(4) MFA(12, 13, 14) MFB(0, 1, 2)
    LOADF(5) MFA(15, 16, 17) MFB(3, 4, 5)
    LOADF(6) MFB(6, 7, 8)
    LOADF(7) MFB(9, 10, 11)
    LOADF(8) MFB(12, 13, 14)
    LOADF(9) MFB(15, 16, 17)
    __builtin_amdgcn_s_setprio(0);
#undef LOADF
#undef MFA
#undef MFB
#define EPI2(CV, YB)                                                          \
  if (epi_ok) {                                                               \
    const int gy = ytile + (YB) + yo;                                         \
    const long i0 = ((long)n4 * IMG + gy) * IMG + gxo;                        \
    out[i0] = fmaxf(CV[0], 0.f) * x[i0];                                      \
    out[i0 + CS] = fmaxf(CV[1], 0.f) * x[i0 + CS];                            \
    out[i0 + 2 * CS] = fmaxf(CV[2], 0.f) * x[i0 + 2 * CS];                    \
    out[i0 + 3 * CS] = fmaxf(CV[3], 0.f) * x[i0 + 3 * CS];                    \
  }
    EPI2(CA, wrow * 8)
    EPI2(CB, wrow * 8 + 4)
#undef EPI2
  };

  // ---- prologue: stage tile 0
  stage_issue(ybase);
  stage_write(xs[0]);
  __syncthreads();

  // ---- 4-tile pipelined loop
#pragma unroll
  for (int ti = 0; ti < 4; ++ti) {
    if (ti < 3) stage_issue(ybase + (ti + 1) * 16);  // HBM hides under conv1
    conv1_tile(xs[ti & 1], ybase + ti * 16);
    __syncthreads();  // hs ready; xs[cur] consumed
    if (ti < 3) stage_write(xs[(ti + 1) & 1]);
    conv2_tile(ybase + ti * 16);
    if (ti < 3) __syncthreads();  // xs[nxt] ready; hs consumed
  }
}

// ---------------------------------------------------------------------------
extern "C" void kernel_launch(void* const* d_in, const int* in_sizes, int n_in,
                              void* d_out, int out_size, void* d_ws,
                              size_t ws_size, hipStream_t stream) {
  const float* x = (const float*)d_in[0];
  const float* w1 = (const float*)d_in[1];
  const float* b1 = (const float*)d_in[2];
  const float* w2 = (const float*)d_in[3];
  const float* b2 = (const float*)d_in[4];
  const float* w_se1 = (const float*)d_in[5];
  const float* b_se1 = (const float*)d_in[6];
  const float* w_se2 = (const float*)d_in[7];
  const float* b_se2 = (const float*)d_in[8];
  float* out = (float*)d_out;
  float* ws = (float*)d_ws;

  // ws: sums[512]f | w1f[1536]bf16 | w2f[147456]bf16 | partials[131072]f
  float* sums = ws;
  unsigned short* w1f = (unsigned short*)(ws + 512);
  unsigned short* w2f = w1f + 1536;
  float* partials = (float*)(w2f + 147456);
  const size_t need_full =
      512 * 4 + 1536 * 2 + (size_t)147456 * 2 + (size_t)131072 * 4;

  k_prep<<<1, 256, 0, stream>>>(w1, w1f);
  if (ws_size >= need_full) {
    k_pool<<<4096, 256, 0, stream>>>(x, w1f, b1, partials, 0);
    k_se<<<16, 256, 0, stream>>>(partials, sums, w_se1, b_se1, w_se2, b_se2,
                                 w2, w2f, 1);
  } else {
    hipMemsetAsync(sums, 0, 512 * sizeof(float), stream);
    k_pool<<<4096, 256, 0, stream>>>(x, w1f, b1, sums, 1);
    k_se<<<16, 256, 0, stream>>>(partials, sums, w_se1, b_se1, w_se2, b_se2,
                                 w2, w2f, 0);
  }
  k_main<<<2304, 256, 0, stream>>>(x, w1f, b1, w2f, b2, out);
}

// Round 10
// 113.098 us; speedup vs baseline: 1.1855x; 1.1855x over previous
//
#include <hip/hip_runtime.h>
#include <math.h>

#define IMG 512

typedef __attribute__((ext_vector_type(4))) short short4_t;
typedef __attribute__((ext_vector_type(8))) short short8;
typedef __attribute__((ext_vector_type(4))) float f32x4;
typedef __attribute__((ext_vector_type(16))) float f32x16;
typedef __attribute__((ext_vector_type(2))) unsigned int u32x2;

__device__ __forceinline__ unsigned short f2bf(float f) {
  unsigned u = __builtin_bit_cast(unsigned, f);
  u += 0x7FFFu + ((u >> 16) & 1u);  // RNE
  return (unsigned short)(u >> 16);
}
// packed f32x2 -> bf16x2 (RNE), single VALU op
__device__ __forceinline__ unsigned cvtpk(float lo, float hi) {
  unsigned r;
  asm("v_cvt_pk_bf16_f32 %0, %1, %2" : "=v"(r) : "v"(lo), "v"(hi));
  return r;
}

// ---------------------------------------------------------------------------
// k_prep: lane-major conv1 A-fragments (32x32x16, K padded 12->16 per kk=dy).
// ---------------------------------------------------------------------------
__global__ __launch_bounds__(256) void k_prep(const float* __restrict__ w1,
                                              unsigned short* __restrict__ w1f) {
  const int t = threadIdx.x;
  if (t < 192) {
    const int kk = t >> 6, lane = t & 63;
    const int oc = lane & 31, hi = lane >> 5;
#pragma unroll
    for (int j = 0; j < 8; ++j) {
      const int dxp = 2 * hi + (j >> 2), ic = j & 3;
      float v = (dxp < 3) ? w1[((oc * 4 + ic) * 3 + kk) * 3 + dxp] : 0.f;
      w1f[(kk * 64 + lane) * 8 + j] = f2bf(v);
    }
  }
}

// ---------------------------------------------------------------------------
// Pass 1: conv1 (bf16 MFMA 32x32x16) + ReLU + pool over exact 32x32 tiles.
// ---------------------------------------------------------------------------
__global__ __launch_bounds__(256, 3) void k_pool(
    const float* __restrict__ x, const unsigned short* __restrict__ w1f,
    const float* __restrict__ b1, float* __restrict__ red_out, int use_atomic) {
  __shared__ unsigned short xs[34 * 40 * 4];
  __shared__ float pools[4][2][16];
  const int bid = blockIdx.x;
  const int swz = (bid & 7) * 512 + (bid >> 3);  // XCD-contiguous
  const int bx = swz & 15, by = (swz >> 4) & 15, n = swz >> 8;
  const int x0 = bx * 32, y0 = by * 32;
  const int t = threadIdx.x, lane = t & 63, wv = t >> 6;
  const int hi = lane >> 5;

  short8 A1[3];
#pragma unroll
  for (int kk = 0; kk < 3; ++kk)
    A1[kk] = *(const short8*)&w1f[(kk * 64 + lane) * 8];
  float bias_r[16];
#pragma unroll
  for (int r = 0; r < 16; ++r) {
    float bl = b1[(r & 3) + 8 * (r >> 2)], bh = b1[(r & 3) + 8 * (r >> 2) + 4];
    bias_r[r] = hi ? bh : bl;
  }

  const int sx = x0 - 4;
  const long CS = (long)IMG * IMG;
  for (int i = t; i < 340; i += 256) {
    const int row = i / 10, cb = i % 10;
    const int gy = y0 - 1 + row, gx0 = sx + cb * 4;
    f32x4 v0 = {0.f, 0.f, 0.f, 0.f}, v1 = v0, v2 = v0, v3 = v0;
    if (gy >= 0 && gy < IMG && gx0 >= 0 && gx0 < IMG) {
      const float* p = x + (((long)(n * 4) * IMG + gy) * IMG + gx0);
      v0 = *(const f32x4*)p;
      v1 = *(const f32x4*)(p + CS);
      v2 = *(const f32x4*)(p + 2 * CS);
      v3 = *(const f32x4*)(p + 3 * CS);
    }
    unsigned short* d = &xs[(row * 40 + cb * 4) * 4];
#pragma unroll
    for (int j = 0; j < 4; ++j) {
      u32x2 w;
      w[0] = cvtpk(v0[j], v1[j]);
      w[1] = cvtpk(v2[j], v3[j]);
      *(u32x2*)(d + j * 4) = w;
    }
  }
  __syncthreads();

  float pacc[16];
#pragma unroll
  for (int r = 0; r < 16; ++r) pacc[r] = 0.f;
  const int cx0 = (lane & 31) + 2 * hi + 3;
  const unsigned short* pP = &xs[((wv * 8) * 40 + cx0) * 4];
#define LOADP(K)                                                              \
  __builtin_shufflevector(*(const short4_t*)(pP + (K)*160),                   \
                          *(const short4_t*)(pP + (K)*160 + 4), 0, 1, 2, 3,   \
                          4, 5, 6, 7)
  short8 Ba, Bb, Bc;
  Ba = LOADP(0);
  Bb = LOADP(1);
#define P_ITER(IT, B0, B1, B2)                                                \
  {                                                                           \
    B2 = LOADP((IT) + 2);                                                     \
    f32x16 C;                                                                 \
    _Pragma("unroll") for (int r = 0; r < 16; ++r) C[r] = bias_r[r];          \
    C = __builtin_amdgcn_mfma_f32_32x32x16_bf16(A1[0], B0, C, 0, 0, 0);       \
    C = __builtin_amdgcn_mfma_f32_32x32x16_bf16(A1[1], B1, C, 0, 0, 0);       \
    C = __builtin_amdgcn_mfma_f32_32x32x16_bf16(A1[2], B2, C, 0, 0, 0);       \
    _Pragma("unroll") for (int r = 0; r < 16; ++r)                            \
        pacc[r] += fmaxf(C[r], 0.f);                                          \
  }
  P_ITER(0, Ba, Bb, Bc)
  P_ITER(1, Bb, Bc, Ba)
  P_ITER(2, Bc, Ba, Bb)
  P_ITER(3, Ba, Bb, Bc)
  P_ITER(4, Bb, Bc, Ba)
  P_ITER(5, Bc, Ba, Bb)
  P_ITER(6, Ba, Bb, Bc)
  P_ITER(7, Bb, Bc, Ba)
#undef P_ITER
#undef LOADP
#pragma unroll
  for (int r = 0; r < 16; ++r) {
#pragma unroll
    for (int m = 1; m < 32; m <<= 1) pacc[r] += __shfl_xor(pacc[r], m);
  }
  if ((lane & 31) == 0) {
#pragma unroll
    for (int r = 0; r < 16; ++r) pools[wv][hi][r] = pacc[r];
  }
  __syncthreads();
  if (t < 32) {
    const int c = t;
    const int hic = (c >> 2) & 1, reg = (c & 3) + 4 * (c >> 3);
    float s = pools[0][hic][reg] + pools[1][hic][reg] + pools[2][hic][reg] +
              pools[3][hic][reg];
    if (use_atomic) {
      atomicAdd(&red_out[n * 32 + c], s);
    } else {
      red_out[(n * 256 + by * 16 + bx) * 32 + c] = s;
    }
  }
}

// ---------------------------------------------------------------------------
// Pass 2: reduce partials (det path) + SE head + emit conv2 A-fragments:
// w2f[((n*18+s)*64+lane)*8+j], s=(dyy*3+dx), lane:(row16=oc+4*yo, cg),
// value = (0<=dyy-yo<3) ? w2[oc][c=cg*8+j][dyy-yo][dx]*p[c] : 0
// ---------------------------------------------------------------------------
__global__ __launch_bounds__(256) void k_se(
    const float* __restrict__ partials, const float* __restrict__ sums,
    const float* __restrict__ w_se1, const float* __restrict__ b_se1,
    const float* __restrict__ w_se2, const float* __restrict__ b_se2,
    const float* __restrict__ w2, unsigned short* __restrict__ w2f, int det) {
  const int n = blockIdx.x, t = threadIdx.x;
  __shared__ float red[8][32];
  __shared__ float mean_s[32], f1[16], p[32];
  if (det) {
    const int c = t & 31, s = t >> 5;
    float a = 0.f;
    for (int i = s * 32; i < s * 32 + 32; ++i)
      a += partials[(n * 256 + i) * 32 + c];
    red[s][c] = a;
    __syncthreads();
    if (t < 32) {
      float v = 0.f;
#pragma unroll
      for (int s2 = 0; s2 < 8; ++s2) v += red[s2][t];
      mean_s[t] = v * (1.0f / (512.f * 512.f));
    }
  } else {
    if (t < 32) mean_s[t] = sums[n * 32 + t] * (1.0f / (512.f * 512.f));
  }
  __syncthreads();
  if (t < 16) {
    float a = b_se1[t];
#pragma unroll
    for (int c = 0; c < 32; ++c) a += w_se1[t * 32 + c] * mean_s[c];
    f1[t] = fmaxf(a, 0.f);
  }
  __syncthreads();
  if (t < 32) {
    float a = b_se2[t];
#pragma unroll
    for (int c = 0; c < 16; ++c) a += w_se2[t * 16 + c] * f1[c];
    p[t] = 1.f / (1.f + expf(-a));
  }
  __syncthreads();
  for (int i = t; i < 9216; i += 256) {
    const int s = i >> 9, rem = i & 511, lane2 = rem >> 3, j = rem & 7;
    const int oc = lane2 & 3, yo = (lane2 >> 2) & 3, cg = lane2 >> 4;
    const int c = cg * 8 + j;
    const int dyy = s / 3, dx = s - dyy * 3, dy = dyy - yo;
    float v = 0.f;
    if (dy >= 0 && dy < 3) v = w2[(oc * 32 + c) * 9 + dy * 3 + dx] * p[c];
    w2f[((n * 18 + s) * 64 + lane2) * 8 + j] = f2bf(v);
  }
}

// ---------------------------------------------------------------------------
// Pass 3: fused conv1(MFMA 32x32x16) -> hs(LDS) -> conv2(MFMA 16x16x32,
// full-M K=576) + residual multiply. SMALL TILE: 30 out cols x 8 out rows
// => LDS 24.3 KB (xs 12 rows + hs 10 rows) => up to 6 blocks/CU resident
// (round-8's 16-row tile = 43.3 KB capped at 3; stall-bound, nothing
// saturated). Per-wave conv2 = ONE 18-MFMA chain (levels 0-5).
// hs [10][32 px][32 c] bf16, swizzle q2=(px>>1)&3 on 16B blocks.
// NO register pinning / persistence (round-9 lesson: forcing A2 live
// caused spill + 3x FETCH). A2 read at use; compiler schedules.
// ---------------------------------------------------------------------------
__global__ __launch_bounds__(256, 5) void k_main(
    const float* __restrict__ x, const unsigned short* __restrict__ w1f,
    const float* __restrict__ b1, const unsigned short* __restrict__ w2f,
    const float* __restrict__ b2, float* __restrict__ out) {
  __shared__ unsigned short xs[12 * 40 * 4];
  __shared__ unsigned short hs[10 * 32 * 32];
  const int bid = blockIdx.x;
  const int swz = (bid & 7) * 2304 + (bid >> 3);  // XCD-contiguous, 18432 wgs
  const int bx = swz % 18;
  const int q = swz / 18;
  const int by = q & 63, n = q >> 6;
  const int x0 = bx * 30, ytile = by * 8;
  const int t = threadIdx.x, lane = t & 63, wv = t >> 6;
  const int hi = lane >> 5;
  const long CS = (long)IMG * IMG;

  short8 A1[3];
#pragma unroll
  for (int kk = 0; kk < 3; ++kk)
    A1[kk] = *(const short8*)&w1f[(kk * 64 + lane) * 8];
  float bias_r[16];
#pragma unroll
  for (int r = 0; r < 16; ++r) {
    float bl = b1[(r & 3) + 8 * (r >> 2)], bh = b1[(r & 3) + 8 * (r >> 2) + 4];
    bias_r[r] = hi ? bh : bl;
  }

  // ---- stage x rows ytile-2 .. ytile+9 (12 rows x 10 col-blocks)
  const int sx = (x0 - 4) & ~3;
  if (t < 120) {
    const int row = t / 10, cb = t % 10;
    const int gy = ytile - 2 + row, gx0 = sx + cb * 4;
    f32x4 v0 = {0.f, 0.f, 0.f, 0.f}, v1 = v0, v2 = v0, v3 = v0;
    if (gy >= 0 && gy < IMG && gx0 >= 0 && gx0 < IMG) {
      const float* p = x + (((long)(n * 4) * IMG + gy) * IMG + gx0);
      v0 = *(const f32x4*)p;
      v1 = *(const f32x4*)(p + CS);
      v2 = *(const f32x4*)(p + 2 * CS);
      v3 = *(const f32x4*)(p + 3 * CS);
    }
    unsigned short* d = &xs[(row * 40 + cb * 4) * 4];
#pragma unroll
    for (int j = 0; j < 4; ++j) {
      u32x2 w;
      w[0] = cvtpk(v0[j], v1[j]);
      w[1] = cvtpk(v2[j], v3[j]);
      *(u32x2*)(d + j * 4) = w;
    }
  }
  __syncthreads();

  // ---- conv1 -> hs rows 0..9 (hs = 0 outside image)
  {
    const int px = lane & 31;
    const int cx0 = px + 2 * hi + (x0 - 2 - sx);  // halo-aware delta
    const int q2 = (px >> 1) & 3;
    const int gxc = x0 - 1 + px;
    const bool colok = (gxc >= 0) && (gxc < IMG);
    const bool col_int = (x0 >= 1) && (x0 + 30 < IMG);
    const int R0 = (wv < 2) ? 3 * wv : 6 + 2 * (wv - 2);  // rows 3,3,2,2
    const unsigned short* pR = &xs[(R0 * 40 + cx0) * 4];
#define LOADX(K)                                                              \
  __builtin_shufflevector(*(const short4_t*)(pR + (K)*160),                   \
                          *(const short4_t*)(pR + (K)*160 + 4), 0, 1, 2, 3,   \
                          4, 5, 6, 7)
    short8 Ba, Bb, Bc;
    Ba = LOADX(0);
    Bb = LOADX(1);
#define C1_ITER(IT, B0, B1, B2)                                               \
  {                                                                           \
    B2 = LOADX((IT) + 2);                                                     \
    const int hy = R0 + (IT);                                                 \
    const int yi = ytile - 1 + hy;                                            \
    const bool row_ok = (yi >= 0) && (yi < IMG);                              \
    f32x16 C;                                                                 \
    _Pragma("unroll") for (int r = 0; r < 16; ++r) C[r] = bias_r[r];          \
    C = __builtin_amdgcn_mfma_f32_32x32x16_bf16(A1[0], B0, C, 0, 0, 0);       \
    C = __builtin_amdgcn_mfma_f32_32x32x16_bf16(A1[1], B1, C, 0, 0, 0);       \
    C = __builtin_amdgcn_mfma_f32_32x32x16_bf16(A1[2], B2, C, 0, 0, 0);       \
    const int usb = hy * 1024 + px * 32 + (hi << 2);                          \
    if (row_ok && col_int) {                                                  \
      _Pragma("unroll") for (int g = 0; g < 4; ++g) {                         \
        u32x2 w;                                                              \
        w[0] = cvtpk(fmaxf(C[4 * g + 0], 0.f), fmaxf(C[4 * g + 1], 0.f));     \
        w[1] = cvtpk(fmaxf(C[4 * g + 2], 0.f), fmaxf(C[4 * g + 3], 0.f));     \
        *(u32x2*)&hs[usb + ((g ^ q2) << 3)] = w;                              \
      }                                                                       \
    } else if (row_ok) {                                                      \
      _Pragma("unroll") for (int g = 0; g < 4; ++g) {                         \
        unsigned p01 =                                                        \
            cvtpk(fmaxf(C[4 * g + 0], 0.f), fmaxf(C[4 * g + 1], 0.f));        \
        unsigned p23 =                                                        \
            cvtpk(fmaxf(C[4 * g + 2], 0.f), fmaxf(C[4 * g + 3], 0.f));        \
        u32x2 w;                                                              \
        w[0] = colok ? p01 : 0u;                                              \
        w[1] = colok ? p23 : 0u;                                              \
        *(u32x2*)&hs[usb + ((g ^ q2) << 3)] = w;                              \
      }                                                                       \
    } else {                                                                  \
      u32x2 z;                                                                \
      z[0] = 0u;                                                              \
      z[1] = 0u;                                                              \
      _Pragma("unroll") for (int g = 0; g < 4; ++g)                           \
          *(u32x2*)&hs[usb + ((g ^ q2) << 3)] = z;                            \
    }                                                                         \
  }
    C1_ITER(0, Ba, Bb, Bc)
    C1_ITER(1, Bb, Bc, Ba)
    if (wv < 2) C1_ITER(2, Bc, Ba, Bb)
#undef C1_ITER
#undef LOADX
  }
  __syncthreads();

  // ---- conv2: one 18-MFMA chain per wave (4 y-rows x 16 px x 4 oc)
  {
    const int px16 = lane & 15, cg = lane >> 4;
    const int grp = wv & 1, wrow = wv >> 1;  // px half, y quad
    const int ox = grp * 16 + px16;
    const int yo = lane >> 4;
    const int gxo = x0 + ox;
    const bool epi_ok = (ox < 30) && (gxo < IMG);
    const float b20 = b2[0], b21 = b2[1], b22 = b2[2], b23 = b2[3];
    int ph0 = ox, ph1 = ox + 1, ph2 = ox + 2;
    ph2 = ph2 < 31 ? ph2 : 31;
    ph1 = ph1 < 31 ? ph1 : 31;
    const int ba0 = ph0 * 64 + ((cg ^ ((ph0 >> 1) & 3)) << 4);
    const int ba1 = ph1 * 64 + ((cg ^ ((ph1 >> 1) & 3)) << 4);
    const int ba2 = ph2 * 64 + ((cg ^ ((ph2 >> 1) & 3)) << 4);
    const char* hb = (const char*)hs + (wrow * 4) * 2048;
    const unsigned short* w2b = w2f + (size_t)n * 9216 + lane * 8;
    f32x4 CA = {b20, b21, b22, b23};  // bias pre-folded
    short8 F0, F1, F2;

#define A2F(S) (*(const short8*)(w2b + (S)*512))
#define LOADF(R)                                                              \
  F0 = *(const short8*)(hb + (R)*2048 + ba0);                                 \
  F1 = *(const short8*)(hb + (R)*2048 + ba1);                                 \
  F2 = *(const short8*)(hb + (R)*2048 + ba2);
#define MFA(S0, S1, S2)                                                       \
  CA = __builtin_amdgcn_mfma_f32_16x16x32_bf16(A2F(S0), F0, CA, 0, 0, 0);     \
  CA = __builtin_amdgcn_mfma_f32_16x16x32_bf16(A2F(S1), F1, CA, 0, 0, 0);     \
  CA = __builtin_amdgcn_mfma_f32_16x16x32_bf16(A2F(S2), F2, CA, 0, 0, 0);

    __builtin_amdgcn_s_setprio(1);
    LOADF(0) MFA(0, 1, 2)
    LOADF(1) MFA(3, 4, 5)
    LOADF(2) MFA(6, 7, 8)
    LOADF(3) MFA(9, 10, 11)
    LOADF(4) MFA(12, 13, 14)
    LOADF(5) MFA(15, 16, 17)
    __builtin_amdgcn_s_setprio(0);
#undef LOADF
#undef MFA
#undef A2F

    if (epi_ok) {
      const int gy = ytile + wrow * 4 + yo;
      const long i0 = ((long)(n * 4) * IMG + gy) * IMG + gxo;
      out[i0] = fmaxf(CA[0], 0.f) * x[i0];
      out[i0 + CS] = fmaxf(CA[1], 0.f) * x[i0 + CS];
      out[i0 + 2 * CS] = fmaxf(CA[2], 0.f) * x[i0 + 2 * CS];
      out[i0 + 3 * CS] = fmaxf(CA[3], 0.f) * x[i0 + 3 * CS];
    }
  }
}

// ---------------------------------------------------------------------------
extern "C" void kernel_launch(void* const* d_in, const int* in_sizes, int n_in,
                              void* d_out, int out_size, void* d_ws,
                              size_t ws_size, hipStream_t stream) {
  const float* x = (const float*)d_in[0];
  const float* w1 = (const float*)d_in[1];
  const float* b1 = (const float*)d_in[2];
  const float* w2 = (const float*)d_in[3];
  const float* b2 = (const float*)d_in[4];
  const float* w_se1 = (const float*)d_in[5];
  const float* b_se1 = (const float*)d_in[6];
  const float* w_se2 = (const float*)d_in[7];
  const float* b_se2 = (const float*)d_in[8];
  float* out = (float*)d_out;
  float* ws = (float*)d_ws;

  // ws: sums[512]f | w1f[1536]bf16 | w2f[147456]bf16 | partials[131072]f
  float* sums = ws;
  unsigned short* w1f = (unsigned short*)(ws + 512);
  unsigned short* w2f = w1f + 1536;
  float* partials = (float*)(w2f + 147456);
  const size_t need_full =
      512 * 4 + 1536 * 2 + (size_t)147456 * 2 + (size_t)131072 * 4;

  k_prep<<<1, 256, 0, stream>>>(w1, w1f);
  if (ws_size >= need_full) {
    k_pool<<<4096, 256, 0, stream>>>(x, w1f, b1, partials, 0);
    k_se<<<16, 256, 0, stream>>>(partials, sums, w_se1, b_se1, w_se2, b_se2,
                                 w2, w2f, 1);
  } else {
    hipMemsetAsync(sums, 0, 512 * sizeof(float), stream);
    k_pool<<<4096, 256, 0, stream>>>(x, w1f, b1, sums, 1);
    k_se<<<16, 256, 0, stream>>>(partials, sums, w_se1, b_se1, w_se2, b_se2,
                                 w2, w2f, 0);
  }
  k_main<<<18432, 256, 0, stream>>>(x, w1f, b1, w2f, b2, out);
}